// Round 3
// baseline (2371.420 us; speedup 1.0000x reference)
//
#include <hip/hip_runtime.h>
#include <stdint.h>

#define T_STEPS 512
#define B_ALL   512
#define SDIM    64
#define HID     128
#define ADIM    10
#define CB      32      // batch rows per chunk
#define NSLOT   4       // h buffer depth (anti-deps at t-3)

typedef __attribute__((ext_vector_type(4))) float f32x4;
typedef __attribute__((ext_vector_type(8))) short s16x8;

#define MFMA(a,b,c) __builtin_amdgcn_mfma_f32_16x16x32_bf16(a,b,c,0,0,0)
#define SC_AGENT __HIP_MEMORY_SCOPE_AGENT

__device__ __forceinline__ unsigned short bf_rne(float f){
    union{float f; unsigned int u;} v; v.f = f;
    unsigned int r = v.u + 0x7fffu + ((v.u >> 16) & 1u);
    return (unsigned short)(r >> 16);
}
__device__ __forceinline__ float us_to_f(unsigned short h){
    union{unsigned int u; float f;} v; v.u = ((unsigned int)h) << 16; return v.f;
}
__device__ __forceinline__ void split_pair(float f, unsigned short& hi, unsigned short& lo){
    hi = bf_rne(f);
    lo = bf_rne(f - us_to_f(hi));
}
__device__ __forceinline__ void load_split8(const float* p, s16x8& h, s16x8& l){
#pragma unroll
    for (int i = 0; i < 8; i++){
        unsigned short a, b; split_pair(p[i], a, b);
        h[i] = (short)a; l[i] = (short)b;
    }
}
__device__ __forceinline__ float sigm(float x){ return 1.f / (1.f + __expf(-x)); }
__device__ __forceinline__ float tanh_f(float x){ return 1.f - 2.f / (__expf(2.f * x) + 1.f); }

// ---- cross-WG relaxed-only protocol, watermark edition ----
// Each producing WAVE owns one 64B-strided watermark slot per chunk-layer
// (16 slots). After its h stores are drained to the coherence point
// (vmcnt(0)), it plain-stores (t+1) into its slot. Consumers poll all 16
// slots in ONE wave-load (lane i reads slot i&15) and min-reduce via
// shfl_xor. This removes the 16-deep same-address atomic-RMW chain of the
// previous counter design while preserving the drain-before-publish
// visibility guarantee (identical ordering argument: data stores ack at
// the coherence point before the watermark store issues).
__device__ __forceinline__ void wait_wm(const uint32_t* wm, uint32_t v, uint32_t& seen, int lane15){
    if (seen >= v) return;                      // monotone shadow: skip poll when known-satisfied
    const uint32_t* p = wm + (size_t)lane15 * 16;   // 64B stride
    for (;;){
        uint32_t c = __hip_atomic_load(p, __ATOMIC_RELAXED, SC_AGENT);
        uint32_t m = c;
#pragma unroll
        for (int off = 8; off; off >>= 1){
            uint32_t o = (uint32_t)__shfl_xor((int)m, off, 16);
            m = m < o ? m : o;                  // min over the 16-slot group
        }
        if (m >= v){ seen = m; break; }         // cache true min: future waits may skip
        __builtin_amdgcn_s_sleep(1);
    }
    __asm__ volatile("" ::: "memory");
}
__device__ __forceinline__ void wm_publish(uint32_t* wm, int slot, uint32_t val){
    __asm__ volatile("" ::: "memory");
    __builtin_amdgcn_s_waitcnt(0x0f70);   // vmcnt(0): this wave's h stores acked at coherence point
    __hip_atomic_store(wm + (size_t)slot * 16, val, __ATOMIC_RELAXED, SC_AGENT);
}
__device__ __forceinline__ void h_store(uint32_t* p, uint32_t v){
    __hip_atomic_store(p, v, __ATOMIC_RELAXED, SC_AGENT);     // write-through sc1
}
// load 8 packed (hi|lo) cols -> hi-frag + lo-frag. p must be 8B aligned.
__device__ __forceinline__ void load_hfrag(const uint32_t* p, s16x8& ah, s16x8& al){
    unsigned long long w[4];
#pragma unroll
    for (int i = 0; i < 4; i++)
        w[i] = __hip_atomic_load((const unsigned long long*)p + i, __ATOMIC_RELAXED, SC_AGENT);
#pragma unroll
    for (int i = 0; i < 4; i++){
        uint32_t a = (uint32_t)w[i], b = (uint32_t)(w[i] >> 32);
        ah[2*i]   = (short)(a >> 16); al[2*i]   = (short)(a & 0xffffu);
        ah[2*i+1] = (short)(b >> 16); al[2*i+1] = (short)(b & 0xffffu);
    }
}

__global__ void __launch_bounds__(256, 1)
lstm_fused(const float* __restrict__ x,
           const float* __restrict__ Wih0, const float* __restrict__ Whh0,
           const float* __restrict__ bih0, const float* __restrict__ bhh0,
           const float* __restrict__ Wih1, const float* __restrict__ Whh1,
           const float* __restrict__ bih1, const float* __restrict__ bhh1,
           const float* __restrict__ Wout, const float* __restrict__ bout,
           float* __restrict__ out, unsigned char* __restrict__ ws)
{
    extern __shared__ char smem[];
    float* part = (float*)smem;                      // 8 slots * 256 f32 = 8 KB

    const int tid  = threadIdx.x;
    const int wave = tid >> 6, lane = tid & 63;
    const int lm = lane & 15, lq = lane >> 4;
    const int mt = wave & 1, kh = wave >> 1;

    const int wg = blockIdx.x;
    const int chunk = wg >> 4, sub = wg & 15;
    const int layer = sub >> 3, slice = sub & 7;
    const int b0 = chunk * CB;

    // ws layout: [0,16KB) wm0 (16 chunks x 16 slots x 64B),
    //            [16KB,32KB) wm1, [32KB,...) h buffers
    uint32_t* wm0 = (uint32_t*)(ws + (size_t)chunk * 1024);
    uint32_t* wm1 = (uint32_t*)(ws + 16384 + (size_t)chunk * 1024);
    uint32_t* h0p = (uint32_t*)(ws + 32768);                 // [NSLOT][512][128] packed hi|lo
    uint32_t* h1p = h0p + (size_t)NSLOT * B_ALL * HID;

    uint32_t seen0 = 0, seen1 = 0;                           // watermark min shadows

    if (layer == 0){
        // ---- layer 0: gates = x @ Wih0^T + h0(t-1) @ Whh0^T ----
        // K = 64 (x: kt 0,1) + 128 (h0: kt 2..5); kh=0 -> kt{0,1,2}, kh=1 -> kt{3,4,5}
        s16x8 wh[4][3], wl[4][3];
#pragma unroll
        for (int g = 0; g < 4; g++)
#pragma unroll
            for (int ktl = 0; ktl < 3; ktl++){
                int kt = kh * 3 + ktl;
                int j = g * HID + slice * 16 + lm;
                const float* src = (kt < 2) ? (Wih0 + (size_t)j * SDIM + kt * 32 + lq * 8)
                                            : (Whh0 + (size_t)j * HID + (kt - 2) * 32 + lq * 8);
                load_split8(src, wh[g][ktl], wl[g][ktl]);
            }
        float bias[4];
#pragma unroll
        for (int g = 0; g < 4; g++){
            int j = g * HID + slice * 16 + lm;
            bias[g] = bih0[j] + bhh0[j];
        }
        float cst[4] = {0.f, 0.f, 0.f, 0.f};

        for (int t = 0; t < T_STEPS; t++){
            // x(t) is dependency-free: issue loads before any wait
            s16x8 Ah[3], Al[3];
            if (kh == 0){
                const float* xp = x + ((size_t)t * B_ALL + b0 + mt * 16 + lm) * SDIM;
                float v[16];
#pragma unroll
                for (int kt = 0; kt < 2; kt++)
#pragma unroll
                    for (int j = 0; j < 8; j++) v[kt * 8 + j] = xp[kt * 32 + lq * 8 + j];
#pragma unroll
                for (int kt = 0; kt < 2; kt++)
#pragma unroll
                    for (int j = 0; j < 8; j++){
                        unsigned short hh, ll; split_pair(v[kt * 8 + j], hh, ll);
                        Ah[kt][j] = (short)hh; Al[kt][j] = (short)ll;
                    }
            }
            if (t > 0) wait_wm(wm0, (uint32_t)t, seen0, lm);          // h0(t-1) ready
            if (t > 3) wait_wm(wm1, (uint32_t)(t - 3), seen1, lm);    // slot t&3 reusable

            const uint32_t* hr = h0p + ((size_t)((t - 1) & 3) * B_ALL + b0 + mt * 16 + lm) * HID;
            if (kh == 0){
                load_hfrag(hr + 0 + lq * 8, Ah[2], Al[2]);           // h0 cols 0..31
            } else {
#pragma unroll
                for (int i = 0; i < 3; i++)
                    load_hfrag(hr + 32 + i * 32 + lq * 8, Ah[i], Al[i]);   // h0 cols 32..127
            }

            f32x4 acc[4];
#pragma unroll
            for (int g = 0; g < 4; g++) acc[g] = (f32x4){0.f, 0.f, 0.f, 0.f};
#pragma unroll
            for (int ktl = 0; ktl < 3; ktl++)
#pragma unroll
                for (int g = 0; g < 4; g++){
                    acc[g] = MFMA(Ah[ktl], wh[g][ktl], acc[g]);
                    acc[g] = MFMA(Ah[ktl], wl[g][ktl], acc[g]);
                    acc[g] = MFMA(Al[ktl], wh[g][ktl], acc[g]);
                }

            if (wave >= 2){
#pragma unroll
                for (int g = 0; g < 4; g++)
                    *(f32x4*)(part + ((wave - 2) * 4 + g) * 256 + lane * 4) = acc[g];
            }
            __syncthreads();
            if (wave < 2){
#pragma unroll
                for (int g = 0; g < 4; g++)
                    acc[g] += *(f32x4*)(part + (wave * 4 + g) * 256 + lane * 4);
                uint32_t* wrow = h0p + ((size_t)(t & 3) * B_ALL + b0 + mt * 16 + lq * 4) * HID
                               + slice * 16 + lm;
#pragma unroll
                for (int r = 0; r < 4; r++){
                    float zi = acc[0][r] + bias[0], zf = acc[1][r] + bias[1];
                    float zg = acc[2][r] + bias[2], zo = acc[3][r] + bias[3];
                    float cn = sigm(zf) * cst[r] + sigm(zi) * tanh_f(zg);
                    float hn = sigm(zo) * tanh_f(cn);
                    cst[r] = cn;
                    unsigned short hh, ll; split_pair(hn, hh, ll);
                    h_store(wrow + (size_t)r * HID, ((uint32_t)hh << 16) | (uint32_t)ll);
                }
                if (lane == 0) wm_publish(wm0, slice * 2 + mt, (uint32_t)(t + 1));
            }
        }
    } else {
        // ---- layer 1: gates = h0(t) @ Wih1^T + h1(t-1) @ Whh1^T; + action(t-1) ----
        // K = 128 (h0: kt 0..3) + 128 (h1: kt 4..7); kh=0 -> h0 half, kh=1 -> h1 half
        s16x8 wh[4][4], wl[4][4];
#pragma unroll
        for (int g = 0; g < 4; g++)
#pragma unroll
            for (int ktl = 0; ktl < 4; ktl++){
                int kt = kh * 4 + ktl;
                int j = g * HID + slice * 16 + lm;
                const float* src = (kt < 4) ? (Wih1 + (size_t)j * HID + kt * 32 + lq * 8)
                                            : (Whh1 + (size_t)j * HID + (kt - 4) * 32 + lq * 8);
                load_split8(src, wh[g][ktl], wl[g][ktl]);
            }
        float bias[4];
#pragma unroll
        for (int g = 0; g < 4; g++){
            int j = g * HID + slice * 16 + lm;
            bias[g] = bih1[j] + bhh1[j];
        }
        float cst[4] = {0.f, 0.f, 0.f, 0.f};

        s16x8 oh[4], ol[4];
        float ob = 0.f;
#pragma unroll
        for (int ktl = 0; ktl < 4; ktl++)
#pragma unroll
            for (int i = 0; i < 8; i++){ oh[ktl][i] = 0; ol[ktl][i] = 0; }
        if (kh == 1 && lm < ADIM){
#pragma unroll
            for (int ktl = 0; ktl < 4; ktl++)
                load_split8(Wout + (size_t)lm * HID + ktl * 32 + lq * 8, oh[ktl], ol[ktl]);
            ob = bout[lm];
        }

        for (int t = 0; t < T_STEPS; t++){
            if (kh == 0) wait_wm(wm0, (uint32_t)(t + 1), seen0, lm);      // h0(t) ready
            else if (t > 0) wait_wm(wm1, (uint32_t)t, seen1, lm);         // h1(t-1) ready

            s16x8 Ah[4], Al[4];
            {
                const uint32_t* hr = (kh == 0)
                    ? (h0p + ((size_t)(t & 3) * B_ALL + b0 + mt * 16 + lm) * HID)
                    : (h1p + ((size_t)((t - 1) & 3) * B_ALL + b0 + mt * 16 + lm) * HID);
#pragma unroll
                for (int i = 0; i < 4; i++)
                    load_hfrag(hr + i * 32 + lq * 8, Ah[i], Al[i]);
            }

            f32x4 acc[4];
#pragma unroll
            for (int g = 0; g < 4; g++) acc[g] = (f32x4){0.f, 0.f, 0.f, 0.f};
#pragma unroll
            for (int ktl = 0; ktl < 4; ktl++)
#pragma unroll
                for (int g = 0; g < 4; g++){
                    acc[g] = MFMA(Ah[ktl], wh[g][ktl], acc[g]);
                    acc[g] = MFMA(Ah[ktl], wl[g][ktl], acc[g]);
                    acc[g] = MFMA(Al[ktl], wh[g][ktl], acc[g]);
                }

            if (wave >= 2){
#pragma unroll
                for (int g = 0; g < 4; g++)
                    *(f32x4*)(part + ((wave - 2) * 4 + g) * 256 + lane * 4) = acc[g];
            }
            __syncthreads();
            if (wave < 2){
#pragma unroll
                for (int g = 0; g < 4; g++)
                    acc[g] += *(f32x4*)(part + (wave * 4 + g) * 256 + lane * 4);
                uint32_t* wrow = h1p + ((size_t)(t & 3) * B_ALL + b0 + mt * 16 + lq * 4) * HID
                               + slice * 16 + lm;
#pragma unroll
                for (int r = 0; r < 4; r++){
                    float zi = acc[0][r] + bias[0], zf = acc[1][r] + bias[1];
                    float zg = acc[2][r] + bias[2], zo = acc[3][r] + bias[3];
                    float cn = sigm(zf) * cst[r] + sigm(zi) * tanh_f(zg);
                    float hn = sigm(zo) * tanh_f(cn);
                    cst[r] = cn;
                    unsigned short hh, ll; split_pair(hn, hh, ll);
                    h_store(wrow + (size_t)r * HID, ((uint32_t)hh << 16) | (uint32_t)ll);
                }
                if (lane == 0) wm_publish(wm1, slice * 2 + mt, (uint32_t)(t + 1));
            } else if (t > 0){
                // action(t-1) = tanh(h1(t-1) @ Wout^T + bout): reuse h1 frags in regs
                f32x4 oacc = (f32x4){0.f, 0.f, 0.f, 0.f};
#pragma unroll
                for (int ktl = 0; ktl < 4; ktl++){
                    oacc = MFMA(Ah[ktl], oh[ktl], oacc);
                    oacc = MFMA(Ah[ktl], ol[ktl], oacc);
                    oacc = MFMA(Al[ktl], oh[ktl], oacc);
                }
                if (lm < ADIM){
#pragma unroll
                    for (int r = 0; r < 4; r++){
                        int b = b0 + mt * 16 + lq * 4 + r;
                        out[((size_t)(t - 1) * B_ALL + b) * ADIM + lm] = tanh_f(oacc[r] + ob);
                    }
                }
            }
        }
        // epilogue: action(511) from h1(511) (slot 511&3 = 3)
        if (kh == 1){
            wait_wm(wm1, (uint32_t)T_STEPS, seen1, lm);
            const uint32_t* hr = h1p + ((size_t)3 * B_ALL + b0 + mt * 16 + lm) * HID;
            s16x8 Ah, Al;
            f32x4 oacc = (f32x4){0.f, 0.f, 0.f, 0.f};
#pragma unroll
            for (int ktl = 0; ktl < 4; ktl++){
                load_hfrag(hr + ktl * 32 + lq * 8, Ah, Al);
                oacc = MFMA(Ah, oh[ktl], oacc);
                oacc = MFMA(Ah, ol[ktl], oacc);
                oacc = MFMA(Al, oh[ktl], oacc);
            }
            if (lm < ADIM){
#pragma unroll
                for (int r = 0; r < 4; r++){
                    int b = b0 + mt * 16 + lq * 4 + r;
                    out[((size_t)(T_STEPS - 1) * B_ALL + b) * ADIM + lm] = tanh_f(oacc[r] + ob);
                }
            }
        }
    }
}

extern "C" void kernel_launch(void* const* d_in, const int* in_sizes, int n_in,
                              void* d_out, int out_size, void* d_ws, size_t ws_size,
                              hipStream_t stream)
{
    (void)in_sizes; (void)n_in; (void)out_size; (void)ws_size;
    const float* x    = (const float*)d_in[0];
    const float* Wih0 = (const float*)d_in[1];
    const float* Whh0 = (const float*)d_in[2];
    const float* bih0 = (const float*)d_in[3];
    const float* bhh0 = (const float*)d_in[4];
    const float* Wih1 = (const float*)d_in[5];
    const float* Whh1 = (const float*)d_in[6];
    const float* bih1 = (const float*)d_in[7];
    const float* bhh1 = (const float*)d_in[8];
    const float* Wout = (const float*)d_in[9];
    const float* bout = (const float*)d_in[10];

    // ws: [0,16KB) wm0 (16 chunks x 16 slots x 64B), [16KB,32KB) wm1,
    //     [32KB, ...) h0/h1 packed(hi|lo) u32 buffers, NSLOT slots each
    const size_t ws_used = 32768 + 2 * (size_t)NSLOT * B_ALL * HID * sizeof(uint32_t); // ~2.1 MB
    hipMemsetAsync(d_ws, 0, ws_used, stream);

    const size_t lds_bytes = 8 * 256 * sizeof(float);   // 8 KB partial-sum buffer
    hipLaunchKernelGGL(lstm_fused, dim3(256), dim3(256), lds_bytes, stream,
                       x, Wih0, Whh0, bih0, bhh0, Wih1, Whh1, bih1, bhh1, Wout, bout,
                       (float*)d_out, (unsigned char*)d_ws);
}